// Round 5
// baseline (55.999 us; speedup 1.0000x reference)
//
#include <hip/hip_runtime.h>
#include <math.h>

// Problem constants (match reference)
constexpr int   B_    = 2048;
constexpr int   L_    = 8192;
constexpr int   G_    = 256;
constexpr float BETA_ = 0.01f;
constexpr float BIG_  = 1024.0f;   // y-flag encoding (validated absmax 0.0 in prior rounds)

constexpr int   SEG   = 1024;               // segment (eighth-row) length
constexpr int   NSEG  = L_ / SEG;           // 8 segment columns
constexpr int   PMAXS = SEG + G_ * 3;       // 1792 padded slots (worst case), u16-safe
constexpr int   RB_N  = 192;                // row-phase count (grid = NSEG * RB_N)

// log(sigmoid(-x)) = -softplus(x) = -(max(x,0) + log(1 + exp(-|x|)))
__device__ __forceinline__ float log_sigmoid_neg(float x) {
    return -(fmaxf(x, 0.0f) + __logf(1.0f + __expf(-fabsf(x))));
}

// Direct global->LDS 16B/lane load: no dest VGPR, vmcnt-counted, cannot be
// re-serialized by regalloc. LDS dest = wave-uniform base + lane*16 (m104).
#define GLOAD_LDS16(gp, lp)                                               \
    __builtin_amdgcn_global_load_lds(                                     \
        (const __attribute__((address_space(1))) unsigned int*)(gp),      \
        (__attribute__((address_space(3))) unsigned int*)(lp), 16, 0, 0)

#define WAITV(n) asm volatile("s_waitcnt vmcnt(" #n ")" ::: "memory")
// LDS-only barrier: drains ds ops, NOT the vmem staging pipeline.
#define LDSBAR() do { asm volatile("s_waitcnt lgkmcnt(0)" ::: "memory"); \
                      __builtin_amdgcn_s_barrier(); } while (0)

// ---------------------------------------------------------------------------
// Prep: counting sort per SEGMENT into padded rank space. Block q handles
// labels [q*1024, (q+1)*1024). offs[q][g+1]-offs[q][g] = ceil(n/4)*4.
// ---------------------------------------------------------------------------
extern "C" __global__ __launch_bounds__(256)
void build_rank_kernel(const int* __restrict__ group_ids,
                       int* __restrict__ g_offs,            // [NSEG][257]
                       unsigned short* __restrict__ g_rank) // [L_], rank within segment
{
    __shared__ int s_cnt[G_];
    __shared__ int s_scan[G_];
    __shared__ int s_cur[G_];

    const int t = threadIdx.x;          // 0..255
    const int q = blockIdx.x;           // 0..7

    s_cnt[t] = 0;
    const int4 ids = ((const int4*)group_ids)[q * 256 + t];   // labels q*1024+4t..+3
    __syncthreads();

    atomicAdd(&s_cnt[ids.x], 1);
    atomicAdd(&s_cnt[ids.y], 1);
    atomicAdd(&s_cnt[ids.z], 1);
    atomicAdd(&s_cnt[ids.w], 1);
    __syncthreads();

    s_scan[t] = (s_cnt[t] + 3) & ~3;    // padded count
    __syncthreads();
    for (int off = 1; off < G_; off <<= 1) {
        int v = 0;
        if (t >= off) v = s_scan[t - off];
        __syncthreads();
        s_scan[t] += v;
        __syncthreads();
    }

    const int excl = s_scan[t] - ((s_cnt[t] + 3) & ~3);       // padded start
    s_cur[t] = excl;
    g_offs[q * (G_ + 1) + t] = excl;
    if (t == 0) g_offs[q * (G_ + 1) + G_] = s_scan[G_ - 1];
    __syncthreads();

    const int l = q * SEG + t * 4;
    g_rank[l + 0] = (unsigned short)atomicAdd(&s_cur[ids.x], 1);
    g_rank[l + 1] = (unsigned short)atomicAdd(&s_cur[ids.y], 1);
    g_rank[l + 2] = (unsigned short)atomicAdd(&s_cur[ids.z], 1);
    g_rank[l + 3] = (unsigned short)atomicAdd(&s_cur[ids.w], 1);
}

// ---------------------------------------------------------------------------
// Main: 1536 persistent-ish blocks x 256 threads. Block (q = bid&7,
// rb = bid>>3) processes segment column q of rows r = rb + 192k (10-11 slabs),
// software-pipelined:
//   issue stage(k+1) -> WAITV(2) -> compute+scatter(k) -> LDSBAR ->
//   phase2+rezero(k) -> atomic -> LDSBAR
// Stage buffers are wave-local (wave w stages & consumes its own 256 floats)
// -> no barrier needed on them; vmcnt counting is exact (2 stage + 1 atomic
// per slab per wave, nothing else in the loop).
// LDS 23.5 KB -> 6 blocks/CU (24 waves, 75% occ); stream never drains except
// at the block tail (amortized over ~11 slabs).
// ---------------------------------------------------------------------------
extern "C" __global__ __launch_bounds__(256, 6)
void meta_loss_kernel(const float* __restrict__ logits,
                      const int*   __restrict__ true_y,
                      const int*   __restrict__ g_offs,
                      const unsigned short* __restrict__ g_rank,
                      float*       __restrict__ partial)   // [B][G]
{
    __shared__ float s_row[PMAXS];       // 7168 B scatter/sum space
    __shared__ float s_L[2][SEG];        // 8192 B staged logits (dbuf)
    __shared__ int   s_Y[2][SEG];        // 8192 B staged true_y (dbuf)

    const int t    = threadIdx.x;        // 0..255
    const int w    = t >> 6;             // wave 0..3
    const int lane = t & 63;
    const int q    = blockIdx.x & (NSEG - 1);   // segment column
    const int rb   = blockIdx.x >> 3;           // 0..191

    // ---- block-invariant state (registers; L2-hot loads, once) ----
    const ushort4 rq = ((const ushort4*)(g_rank + q * SEG))[t];  // ranks of elems 4t..4t+3
    const int o0 = g_offs[q * (G_ + 1) + t];
    const int o1 = g_offs[q * (G_ + 1) + t + 1];

    const int nslab = (rb < (B_ - 10 * RB_N)) ? 11 : 10;   // rows rb+192k < 2048

    // ---- zero scatter space once (448 float4) ----
    float4* s_row4 = (float4*)s_row;
    s_row4[t] = make_float4(0.f, 0.f, 0.f, 0.f);
    if (t < PMAXS / 4 - 256) s_row4[256 + t] = make_float4(0.f, 0.f, 0.f, 0.f);

    // ---- prologue: stage slab 0 (wave-local: wave w -> floats [256w,256w+256)) ----
    const size_t colf = (size_t)q * SEG;
    {
        const float* lg = logits + (size_t)rb * L_ + colf;
        const int*   ty = true_y + (size_t)rb * L_ + colf;
        GLOAD_LDS16(lg + w * 256 + lane * 4, &s_L[0][w * 256]);
        GLOAD_LDS16(ty + w * 256 + lane * 4, &s_Y[0][w * 256]);
    }
    LDSBAR();   // zero-init visible to all waves before any scatter

    for (int k = 0; k < nslab; ++k) {
        const int r   = rb + RB_N * k;
        const int cur = k & 1;

        if (k + 1 < nslab) {
            // issue next slab's staging, then wait for CURRENT slab only:
            // outstanding after wait <= 2 = the two newest (slab k+1);
            // everything older (stage k, atomic k-1) is forced complete.
            const int rn = r + RB_N;
            const float* lg = logits + (size_t)rn * L_ + colf;
            const int*   ty = true_y + (size_t)rn * L_ + colf;
            GLOAD_LDS16(lg + w * 256 + lane * 4, &s_L[cur ^ 1][w * 256]);
            GLOAD_LDS16(ty + w * 256 + lane * 4, &s_Y[cur ^ 1][w * 256]);
            WAITV(2);
        } else {
            WAITV(0);                     // tail: drain everything
        }

        // ---- compute + scatter: thread t owns elems 4t..4t+3 (own wave's region) ----
        const float4 X = ((const float4*)s_L[cur])[t];
        const int4   Y = ((const int4*)s_Y[cur])[t];
        s_row[rq.x] = log_sigmoid_neg(X.x) + (Y.x ? BIG_ : 0.0f);
        s_row[rq.y] = log_sigmoid_neg(X.y) + (Y.y ? BIG_ : 0.0f);
        s_row[rq.z] = log_sigmoid_neg(X.z) + (Y.z ? BIG_ : 0.0f);
        s_row[rq.w] = log_sigmoid_neg(X.w) + (Y.w ? BIG_ : 0.0f);
        LDSBAR();                         // scatter visible

        // ---- phase 2: group t's padded extent; fused re-zero ----
        float4 a4 = make_float4(0.f, 0.f, 0.f, 0.f);
        for (int j = o0; j < o1; j += 4) {
            const float4 v = *(const float4*)&s_row[j];
            a4.x += v.x; a4.y += v.y; a4.z += v.z; a4.w += v.w;
            *(float4*)&s_row[j] = make_float4(0.f, 0.f, 0.f, 0.f);
        }
        const float enc = (a4.x + a4.y) + (a4.z + a4.w);
        if (o1 > o0)
            atomicAdd(&partial[r * G_ + t], enc);
        LDSBAR();                         // re-zero visible before next scatter
    }
}

// ---------------------------------------------------------------------------
// Finalize: decode BIG encoding, BCE terms, global reduce. 2 MB read, tiny.
// ---------------------------------------------------------------------------
extern "C" __global__ __launch_bounds__(1024)
void finalize_kernel(const float* __restrict__ partial,
                     float* __restrict__ out)
{
    __shared__ float s_part[16];

    const int t   = threadIdx.x;
    const int idx = blockIdx.x * 1024 + t;    // 512 blocks x 1024 = 524288

    const float enc = partial[idx];
    const int   k   = __float2int_rn(enc * (1.0f / BIG_));   // # true labels
    const float gl  = enc - BIG_ * (float)k;                 // sum log(1-sig)

    float term;
    if (k != 0) {
        term = fmaxf(gl, -100.0f);                    // meta_y = 1: log(p)
    } else {
        // empty/all-false group: gl==0 -> log1p(-1) = -inf -> clamp to -100
        term = fmaxf(log1pf(-__expf(gl)), -100.0f);   // meta_y = 0
    }

    #pragma unroll
    for (int off = 32; off > 0; off >>= 1)
        term += __shfl_down(term, off, 64);
    if ((t & 63) == 0) s_part[t >> 6] = term;
    __syncthreads();

    if (t == 0) {
        float s = 0.0f;
        #pragma unroll
        for (int w = 0; w < 16; ++w) s += s_part[w];
        atomicAdd(out, s * (-BETA_ / ((float)B_ * (float)G_)));
    }
}

extern "C" void kernel_launch(void* const* d_in, const int* in_sizes, int n_in,
                              void* d_out, int out_size, void* d_ws, size_t ws_size,
                              hipStream_t stream) {
    const float* logits    = (const float*)d_in[0];
    const int*   true_y    = (const int*)d_in[1];
    const int*   group_ids = (const int*)d_in[2];
    float*       out       = (float*)d_out;

    // workspace: [0,2MB) partial f32; [2MB,+16KB) rank u16; then offs [8][257]
    float*          partial = (float*)d_ws;
    unsigned short* g_rank  = (unsigned short*)((char*)d_ws + (size_t)B_ * G_ * 4);
    int*            g_offs  = (int*)((char*)d_ws + (size_t)B_ * G_ * 4 + L_ * 2);

    hipMemsetAsync(partial, 0, (size_t)B_ * G_ * 4, stream);
    hipMemsetAsync(out, 0, sizeof(float), stream);

    build_rank_kernel<<<NSEG, 256, 0, stream>>>(group_ids, g_offs, g_rank);
    meta_loss_kernel<<<NSEG * RB_N, 256, 0, stream>>>(logits, true_y, g_offs, g_rank, partial);
    finalize_kernel<<<(B_ * G_) / 1024, 1024, 0, stream>>>(partial, out);
}